// Round 3
// baseline (924.499 us; speedup 1.0000x reference)
//
#include <hip/hip_runtime.h>
#include <hip/hip_bf16.h>

typedef unsigned short u16;
typedef unsigned int u32;
typedef __attribute__((ext_vector_type(8))) short short8;
typedef __attribute__((ext_vector_type(4))) float f32x4;

#define B_ 4
#define T_ 2048
#define D_ 1024
#define H_ 16
#define HS_ 64
#define BT (B_*T_)

__device__ __forceinline__ float bf2f(u16 b){ union{u32 u; float f;} v; v.u=((u32)b)<<16; return v.f; }
__device__ __forceinline__ u16 f2bf(float f){
    __hip_bfloat16 h = __float2bfloat16(f);
    union{__hip_bfloat16 h; u16 u;} v; v.h = h; return v.u;
}
// split f32 into hi/lo bf16: x ~= hi + lo, residual ~2^-17 relative
__device__ __forceinline__ void split2(float x, u16& h, u16& l){
    u16 hb = f2bf(x);
    float fh = bf2f(hb);
    h = hb; l = f2bf(x - fh);
}

union U4 { u16 s[4]; uint2 v; };
union S8 { u16 s[8]; short8 v; };

// ---- pack: Wt[n][d] = W_z[h][d][e], n = z*1024 + h*64 + e (f32, B^T layout) ----
__global__ __launch_bounds__(256) void pack_w(const float* __restrict__ Wq,
                                              const float* __restrict__ Wk,
                                              const float* __restrict__ Wv,
                                              float* __restrict__ Wt)
{
    __shared__ float Tl[64*68];  // [d_local][e], stride 68 (272B = 17*16, float4-aligned)
    const int h = blockIdx.x, dt = blockIdx.y, z = blockIdx.z;
    const float* src = (z==0) ? Wq : ((z==1) ? Wk : Wv);
    const int t = threadIdx.x;
    const int d0 = dt*64;
    #pragma unroll
    for (int i=0;i<4;++i){
        int ci = t + 256*i;              // 1024 float4 chunks
        int dr = ci>>4, ec = ci&15;
        float4 v = *(const float4*)(src + ((size_t)h*D_ + d0+dr)*HS_ + ec*4);
        *(float4*)(Tl + dr*68 + ec*4) = v;
    }
    __syncthreads();
    #pragma unroll
    for (int i=0;i<4;++i){
        int ci = t + 256*i;
        int e = ci>>4, dc = ci&15;
        float4 o;
        o.x = Tl[(dc*4+0)*68 + e];
        o.y = Tl[(dc*4+1)*68 + e];
        o.z = Tl[(dc*4+2)*68 + e];
        o.w = Tl[(dc*4+3)*68 + e];
        int n = z*D_ + h*HS_ + e;
        *(float4*)(Wt + (size_t)n*D_ + d0 + dc*4) = o;
    }
}

// ---- C[M,N] = A[M,K] * Bt[N,K]^T (+bias), f32 in/out, bf16x2 split MFMA ----
// 128x128 tile, BK=32, 4 waves, each wave 64x64 (4x4 of 16x16x32), 3 MFMAs/pair
__global__ __launch_bounds__(256) void gemm_bt(const float* __restrict__ A,
                                               const float* __restrict__ Bt,
                                               float* __restrict__ C,
                                               const float* __restrict__ bias,
                                               int M, int N, int K)
{
    __shared__ u16 Ash[128*32], Asl[128*32];
    __shared__ u16 Bsh[128*32], Bsl[128*32];
    const int n0 = blockIdx.x*128, m0 = blockIdx.y*128;
    const int t = threadIdx.x;
    const int w = t>>6, lane = t&63, quad = lane>>4, l16 = lane&15;
    const int wm = (w>>1)*64, wn = (w&1)*64;
    f32x4 acc[4][4];
    #pragma unroll
    for (int i=0;i<4;++i)
        #pragma unroll
        for (int j=0;j<4;++j) acc[i][j] = (f32x4){0.f,0.f,0.f,0.f};
    const int kT = K >> 5;
    for (int kt=0; kt<kT; ++kt){
        const int k0 = kt*32;
        #pragma unroll
        for (int i=0;i<4;++i){
            int ci = t + 256*i;           // 1024 float4 chunks per matrix
            int row = ci>>3, c4 = ci&7;   // 8 chunks per 32-wide row
            float4 av = *(const float4*)(A  + (size_t)(m0+row)*K + k0 + c4*4);
            float4 bv = *(const float4*)(Bt + (size_t)(n0+row)*K + k0 + c4*4);
            U4 ah, al, bh, bl;
            split2(av.x, ah.s[0], al.s[0]); split2(av.y, ah.s[1], al.s[1]);
            split2(av.z, ah.s[2], al.s[2]); split2(av.w, ah.s[3], al.s[3]);
            split2(bv.x, bh.s[0], bl.s[0]); split2(bv.y, bh.s[1], bl.s[1]);
            split2(bv.z, bh.s[2], bl.s[2]); split2(bv.w, bh.s[3], bl.s[3]);
            *(uint2*)(Ash + row*32 + c4*4) = ah.v;
            *(uint2*)(Asl + row*32 + c4*4) = al.v;
            *(uint2*)(Bsh + row*32 + c4*4) = bh.v;
            *(uint2*)(Bsl + row*32 + c4*4) = bl.v;
        }
        __syncthreads();
        short8 afh[4], afl[4], bfh[4], bfl[4];
        #pragma unroll
        for (int mi=0;mi<4;++mi){
            afh[mi] = *(const short8*)(Ash + (wm+mi*16+l16)*32 + quad*8);
            afl[mi] = *(const short8*)(Asl + (wm+mi*16+l16)*32 + quad*8);
        }
        #pragma unroll
        for (int ni=0;ni<4;++ni){
            bfh[ni] = *(const short8*)(Bsh + (wn+ni*16+l16)*32 + quad*8);
            bfl[ni] = *(const short8*)(Bsl + (wn+ni*16+l16)*32 + quad*8);
        }
        #pragma unroll
        for (int mi=0;mi<4;++mi)
            #pragma unroll
            for (int ni=0;ni<4;++ni){
                acc[mi][ni] = __builtin_amdgcn_mfma_f32_16x16x32_bf16(afh[mi], bfh[ni], acc[mi][ni], 0,0,0);
                acc[mi][ni] = __builtin_amdgcn_mfma_f32_16x16x32_bf16(afh[mi], bfl[ni], acc[mi][ni], 0,0,0);
                acc[mi][ni] = __builtin_amdgcn_mfma_f32_16x16x32_bf16(afl[mi], bfh[ni], acc[mi][ni], 0,0,0);
            }
        __syncthreads();
    }
    #pragma unroll
    for (int ni=0;ni<4;++ni){
        const int col = n0 + wn + ni*16 + l16;
        const float bv = bias ? bias[col] : 0.f;
        #pragma unroll
        for (int mi=0;mi<4;++mi){
            const int row = m0 + wm + mi*16 + quad*4;
            #pragma unroll
            for (int r=0;r<4;++r)
                C[(size_t)(row+r)*N + col] = acc[mi][ni][r] + bv;
        }
    }
}

// ---- causal flash attention over qkv f32 [BT,3072]; out att f32 [BT,1024] ----
__global__ __launch_bounds__(256) void attn(const float* __restrict__ qkv,
                                            float* __restrict__ att)
{
    __shared__ u16 Ksh[64*64], Ksl[64*64];     // [kv][e]
    __shared__ u16 Vth[64*72], Vtl[64*72];     // [e][kv], pad 8
    __shared__ u16 Pwh[4*16*72], Pwl[4*16*72]; // per-wave P staging
    const int qi = blockIdx.x;
    const int bh = blockIdx.y;
    const int b = bh >> 4, h = bh & 15;
    const int t = threadIdx.x;
    const int w = t>>6, lane = t&63, quad = lane>>4, l16 = lane&15;
    const int qr0 = qi*64 + w*16;

    short8 qh[2], ql[2];
    {
        const float* qrow = qkv + (size_t)(b*T_ + qr0 + l16)*3072 + h*64;
        #pragma unroll
        for (int ks=0;ks<2;++ks){
            float4 a0 = *(const float4*)(qrow + ks*32 + quad*8);
            float4 a1 = *(const float4*)(qrow + ks*32 + quad*8 + 4);
            S8 hh, ll;
            split2(a0.x, hh.s[0], ll.s[0]); split2(a0.y, hh.s[1], ll.s[1]);
            split2(a0.z, hh.s[2], ll.s[2]); split2(a0.w, hh.s[3], ll.s[3]);
            split2(a1.x, hh.s[4], ll.s[4]); split2(a1.y, hh.s[5], ll.s[5]);
            split2(a1.z, hh.s[6], ll.s[6]); split2(a1.w, hh.s[7], ll.s[7]);
            qh[ks] = hh.v; ql[ks] = ll.v;
        }
    }
    f32x4 o[4];
    #pragma unroll
    for (int i=0;i<4;++i) o[i] = (f32x4){0.f,0.f,0.f,0.f};
    float m_i[4], l_i[4];
    #pragma unroll
    for (int r=0;r<4;++r){ m_i[r] = -INFINITY; l_i[r] = 0.f; }

    u16* Pmh = Pwh + w*(16*72);
    u16* Pml = Pwl + w*(16*72);

    for (int kvt=0; kvt<=qi; ++kvt){
        __syncthreads();                       // protect Ks/Vt/P from prev-iter readers
        const size_t kbase = (size_t)(b*T_ + kvt*64);
        #pragma unroll
        for (int i=0;i<4;++i){                 // K tile: load f32, split to LDS
            int ci = t + 256*i;
            int row = ci>>4, c4 = ci&15;
            float4 kv4 = *(const float4*)(qkv + (kbase+row)*3072 + 1024 + h*64 + c4*4);
            U4 hh, ll;
            split2(kv4.x, hh.s[0], ll.s[0]); split2(kv4.y, hh.s[1], ll.s[1]);
            split2(kv4.z, hh.s[2], ll.s[2]); split2(kv4.w, hh.s[3], ll.s[3]);
            *(uint2*)(Ksh + row*64 + c4*4) = hh.v;
            *(uint2*)(Ksl + row*64 + c4*4) = ll.v;
        }
        #pragma unroll
        for (int i=0;i<4;++i){                 // V tile: transpose + split
            int ci = t + 256*i;
            int row = ci>>4, c4 = ci&15;
            float4 vv4 = *(const float4*)(qkv + (kbase+row)*3072 + 2048 + h*64 + c4*4);
            const float* pv = (const float*)&vv4;
            #pragma unroll
            for (int j=0;j<4;++j){
                u16 hh, ll; split2(pv[j], hh, ll);
                Vth[(c4*4+j)*72 + row] = hh;
                Vtl[(c4*4+j)*72 + row] = ll;
            }
        }
        __syncthreads();

        // S = Q K^T (M=16 q rows, N=64 kv, K=64), bf16x2: 3 MFMAs per chunk
        float s[4][4];
        #pragma unroll
        for (int ni=0;ni<4;++ni){
            f32x4 sa = (f32x4){0.f,0.f,0.f,0.f};
            #pragma unroll
            for (int ks=0;ks<2;++ks){
                short8 kh = *(const short8*)(Ksh + (ni*16+l16)*64 + ks*32 + quad*8);
                short8 kl = *(const short8*)(Ksl + (ni*16+l16)*64 + ks*32 + quad*8);
                sa = __builtin_amdgcn_mfma_f32_16x16x32_bf16(qh[ks], kh, sa, 0,0,0);
                sa = __builtin_amdgcn_mfma_f32_16x16x32_bf16(qh[ks], kl, sa, 0,0,0);
                sa = __builtin_amdgcn_mfma_f32_16x16x32_bf16(ql[ks], kh, sa, 0,0,0);
            }
            #pragma unroll
            for (int r=0;r<4;++r) s[ni][r] = sa[r]*0.125f;   // 1/sqrt(64)
        }
        if (kvt == qi){                        // causal mask, diagonal tile only
            #pragma unroll
            for (int ni=0;ni<4;++ni){
                int colrel = ni*16 + l16;
                #pragma unroll
                for (int r=0;r<4;++r){
                    int rowrel = w*16 + quad*4 + r;
                    if (colrel > rowrel) s[ni][r] = -INFINITY;
                }
            }
        }
        // online softmax (row lives across the 16 lanes of a quad)
        float mnew[4], alpha[4];
        #pragma unroll
        for (int r=0;r<4;++r){
            float rm = fmaxf(fmaxf(s[0][r],s[1][r]), fmaxf(s[2][r],s[3][r]));
            #pragma unroll
            for (int off=1; off<16; off<<=1) rm = fmaxf(rm, __shfl_xor(rm, off));
            mnew[r] = fmaxf(m_i[r], rm);
            alpha[r] = __expf(m_i[r] - mnew[r]);
        }
        float p[4][4];
        #pragma unroll
        for (int ni=0;ni<4;++ni)
            #pragma unroll
            for (int r=0;r<4;++r) p[ni][r] = __expf(s[ni][r] - mnew[r]);
        #pragma unroll
        for (int r=0;r<4;++r){
            float rs = p[0][r]+p[1][r]+p[2][r]+p[3][r];
            #pragma unroll
            for (int off=1; off<16; off<<=1) rs += __shfl_xor(rs, off);
            l_i[r] = l_i[r]*alpha[r] + rs;
            m_i[r] = mnew[r];
        }
        #pragma unroll
        for (int ni=0;ni<4;++ni)
            #pragma unroll
            for (int r=0;r<4;++r) o[ni][r] *= alpha[r];
        // P: C-layout -> LDS (hi/lo) -> A-layout
        #pragma unroll
        for (int ni=0;ni<4;++ni)
            #pragma unroll
            for (int r=0;r<4;++r){
                u16 hh, ll; split2(p[ni][r], hh, ll);
                Pmh[(quad*4+r)*72 + ni*16 + l16] = hh;
                Pml[(quad*4+r)*72 + ni*16 + l16] = ll;
            }
        __syncthreads();   // fence scalar writes vs vector reads (TBAA)
        short8 pah[2], pal[2];
        #pragma unroll
        for (int ks=0;ks<2;++ks){
            pah[ks] = *(const short8*)(Pmh + l16*72 + ks*32 + quad*8);
            pal[ks] = *(const short8*)(Pml + l16*72 + ks*32 + quad*8);
        }
        #pragma unroll
        for (int ni=0;ni<4;++ni){
            #pragma unroll
            for (int ks=0;ks<2;++ks){
                short8 vh = *(const short8*)(Vth + (ni*16+l16)*72 + ks*32 + quad*8);
                short8 vl = *(const short8*)(Vtl + (ni*16+l16)*72 + ks*32 + quad*8);
                o[ni] = __builtin_amdgcn_mfma_f32_16x16x32_bf16(pah[ks], vh, o[ni], 0,0,0);
                o[ni] = __builtin_amdgcn_mfma_f32_16x16x32_bf16(pah[ks], vl, o[ni], 0,0,0);
                o[ni] = __builtin_amdgcn_mfma_f32_16x16x32_bf16(pal[ks], vh, o[ni], 0,0,0);
            }
        }
    }
    const size_t ob = (size_t)(b*T_ + qr0);
    #pragma unroll
    for (int ni=0;ni<4;++ni){
        const int col = h*64 + ni*16 + l16;
        #pragma unroll
        for (int r=0;r<4;++r)
            att[(ob + quad*4 + r)*1024 + col] = o[ni][r] / l_i[r];
    }
}

extern "C" void kernel_launch(void* const* d_in, const int* in_sizes, int n_in,
                              void* d_out, int out_size, void* d_ws, size_t ws_size,
                              hipStream_t stream)
{
    const float* x  = (const float*)d_in[0];
    const float* Wq = (const float*)d_in[1];
    const float* Wk = (const float*)d_in[2];
    const float* Wv = (const float*)d_in[3];
    const float* Wp = (const float*)d_in[4];
    const float* bp = (const float*)d_in[5];
    float* out = (float*)d_out;
    float* ws  = (float*)d_ws;

    float* qkv = ws;                          // [8192,3072] f32 (96 MB)
    float* att = qkv + (size_t)BT*3072;       // [8192,1024] f32 (32 MB)
    float* Wt  = att;                         // [3072,1024] f32 (12 MB) — dead before attn writes att

    pack_w<<<dim3(16,16,3), 256, 0, stream>>>(Wq, Wk, Wv, Wt);
    gemm_bt<<<dim3(3072/128, BT/128), 256, 0, stream>>>(x, Wt, qkv, nullptr, BT, 3072, 1024);
    attn<<<dim3(T_/64, B_*H_), 256, 0, stream>>>(qkv, att);
    gemm_bt<<<dim3(1024/128, BT/128), 256, 0, stream>>>(att, Wp, out, bp, BT, 1024, 1024);
}

// Round 5
// 707.058 us; speedup vs baseline: 1.3075x; 1.3075x over previous
//
#include <hip/hip_runtime.h>
#include <hip/hip_bf16.h>

typedef unsigned short u16;
typedef unsigned int u32;
typedef __attribute__((ext_vector_type(8))) short short8;
typedef __attribute__((ext_vector_type(4))) float f32x4;

#define B_ 4
#define T_ 2048
#define D_ 1024
#define H_ 16
#define HS_ 64
#define BT (B_*T_)

__device__ __forceinline__ float bf2f(u16 b){ union{u32 u; float f;} v; v.u=((u32)b)<<16; return v.f; }
__device__ __forceinline__ u16 f2bf(float f){
    __hip_bfloat16 h = __float2bfloat16(f);
    union{__hip_bfloat16 h; u16 u;} v; v.h = h; return v.u;
}
// split f32 into hi/lo bf16: x ~= hi + lo
__device__ __forceinline__ void split2(float x, u16& h, u16& l){
    u16 hb = f2bf(x);
    float fh = bf2f(hb);
    h = hb; l = f2bf(x - fh);
}
union U4 { u16 s[4]; uint2 v; };
union S8 { u16 s[8]; short8 v; };

// async global->LDS, 16B per lane; LDS dest wave-linear (base + lane*16)
#define GLD16(g,l) __builtin_amdgcn_global_load_lds( \
    (__attribute__((address_space(1))) void*)(u16*)(g), \
    (__attribute__((address_space(3))) void*)(l), 16, 0, 0)

// XOR-swizzled offset into a row-major [R][64]-u16 LDS tile, 16B-chunk granularity.
// Element (row, col): chunk c = col>>3 placed at c^(row&7). Readers/writers must agree.
__device__ __forceinline__ int swz(int row, int col){
    return row*64 + (((col>>3) ^ (row&7))<<3) + (col&7);
}

// ---- pack: Wt[n][d] (split hi/lo) = W_z[h][d][e], n = z*1024 + h*64 + e ----
__global__ __launch_bounds__(256) void pack_w(const float* __restrict__ Wq,
                                              const float* __restrict__ Wk,
                                              const float* __restrict__ Wv,
                                              u16* __restrict__ Wth,
                                              u16* __restrict__ Wtl)
{
    __shared__ float Tl[64*68];
    const int h = blockIdx.x, dt = blockIdx.y, z = blockIdx.z;
    const float* src = (z==0) ? Wq : ((z==1) ? Wk : Wv);
    const int t = threadIdx.x;
    const int d0 = dt*64;
    #pragma unroll
    for (int i=0;i<4;++i){
        int ci = t + 256*i;
        int dr = ci>>4, ec = ci&15;
        float4 v = *(const float4*)(src + ((size_t)h*D_ + d0+dr)*HS_ + ec*4);
        *(float4*)(Tl + dr*68 + ec*4) = v;
    }
    __syncthreads();
    #pragma unroll
    for (int i=0;i<4;++i){
        int ci = t + 256*i;
        int e = ci>>4, dc = ci&15;
        U4 hh, ll;
        #pragma unroll
        for (int j=0;j<4;++j){
            float f = Tl[(dc*4+j)*68 + e];
            split2(f, hh.s[j], ll.s[j]);
        }
        int n = z*D_ + h*HS_ + e;
        *(uint2*)(Wth + (size_t)n*D_ + d0 + dc*4) = hh.v;
        *(uint2*)(Wtl + (size_t)n*D_ + d0 + dc*4) = ll.v;
    }
}

// ---- QKV GEMM: qkv[t][col] = x[t][:]·Wt[col][:], col in [0,3072) ----
// A: f32 x, split in staging. B: pre-split Wth/Wtl via global_load_lds.
// Epilogue: z=0 -> q f32 [t][n]; z=1 -> kh/kl u16 [t][n]; z=2 -> vt hi/lo [bh][e][t]
__global__ __launch_bounds__(256) void gemm_qkv(const float* __restrict__ x,
                                                const u16* __restrict__ Wth,
                                                const u16* __restrict__ Wtl,
                                                float* __restrict__ qo,
                                                u16* __restrict__ kho, u16* __restrict__ klo,
                                                u16* __restrict__ vth, u16* __restrict__ vtl)
{
    __shared__ u16 Ash[128*32], Asl[128*32];
    __shared__ u16 Bsh[128*32], Bsl[128*32];
    const int n0 = blockIdx.x*128, m0 = blockIdx.y*128;
    const int t = threadIdx.x;
    const int w = t>>6, lane = t&63, quad = lane>>4, l16 = lane&15;
    const int wm = (w>>1)*64, wn = (w&1)*64;
    f32x4 acc[4][4];
    #pragma unroll
    for (int i=0;i<4;++i)
        #pragma unroll
        for (int j=0;j<4;++j) acc[i][j] = (f32x4){0.f,0.f,0.f,0.f};
    for (int kt=0; kt<32; ++kt){
        const int k0 = kt*32;
        #pragma unroll
        for (int i=0;i<2;++i){           // B: async 16B chunks, wave-linear LDS dest
            int ci = t + 256*i;
            int row = ci>>2, c = ci&3;
            GLD16(Wth + (size_t)(n0+row)*D_ + k0 + c*8, Bsh + ci*8);
            GLD16(Wtl + (size_t)(n0+row)*D_ + k0 + c*8, Bsl + ci*8);
        }
        #pragma unroll
        for (int i=0;i<4;++i){           // A: f32 load + split
            int ci = t + 256*i;
            int row = ci>>3, c4 = ci&7;
            float4 av = *(const float4*)(x + (size_t)(m0+row)*D_ + k0 + c4*4);
            U4 hh, ll;
            split2(av.x, hh.s[0], ll.s[0]); split2(av.y, hh.s[1], ll.s[1]);
            split2(av.z, hh.s[2], ll.s[2]); split2(av.w, hh.s[3], ll.s[3]);
            *(uint2*)(Ash + row*32 + c4*4) = hh.v;
            *(uint2*)(Asl + row*32 + c4*4) = ll.v;
        }
        __syncthreads();
        short8 afh[4], afl[4], bfh[4], bfl[4];
        #pragma unroll
        for (int mi=0;mi<4;++mi){
            afh[mi] = *(const short8*)(Ash + (wm+mi*16+l16)*32 + quad*8);
            afl[mi] = *(const short8*)(Asl + (wm+mi*16+l16)*32 + quad*8);
        }
        #pragma unroll
        for (int ni=0;ni<4;++ni){
            bfh[ni] = *(const short8*)(Bsh + (wn+ni*16+l16)*32 + quad*8);
            bfl[ni] = *(const short8*)(Bsl + (wn+ni*16+l16)*32 + quad*8);
        }
        #pragma unroll
        for (int mi=0;mi<4;++mi)
            #pragma unroll
            for (int ni=0;ni<4;++ni){
                acc[mi][ni] = __builtin_amdgcn_mfma_f32_16x16x32_bf16(afh[mi], bfh[ni], acc[mi][ni], 0,0,0);
                acc[mi][ni] = __builtin_amdgcn_mfma_f32_16x16x32_bf16(afh[mi], bfl[ni], acc[mi][ni], 0,0,0);
                acc[mi][ni] = __builtin_amdgcn_mfma_f32_16x16x32_bf16(afl[mi], bfh[ni], acc[mi][ni], 0,0,0);
            }
        __syncthreads();
    }
    const int z = n0 >> 10;              // block-uniform (128 | 1024)
    if (z == 0){
        #pragma unroll
        for (int ni=0;ni<4;++ni){
            const int nloc = (n0 & 1023) + wn + ni*16 + l16;
            #pragma unroll
            for (int mi=0;mi<4;++mi){
                const int row = m0 + wm + mi*16 + quad*4;
                #pragma unroll
                for (int r=0;r<4;++r)
                    qo[(size_t)(row+r)*D_ + nloc] = acc[mi][ni][r];
            }
        }
    } else if (z == 1){
        #pragma unroll
        for (int ni=0;ni<4;++ni){
            const int nloc = (n0 & 1023) + wn + ni*16 + l16;
            #pragma unroll
            for (int mi=0;mi<4;++mi){
                const int row = m0 + wm + mi*16 + quad*4;
                #pragma unroll
                for (int r=0;r<4;++r){
                    u16 hh, ll; split2(acc[mi][ni][r], hh, ll);
                    kho[(size_t)(row+r)*D_ + nloc] = hh;
                    klo[(size_t)(row+r)*D_ + nloc] = ll;
                }
            }
        }
    } else {
        #pragma unroll
        for (int ni=0;ni<4;++ni){
            const int nloc = (n0 & 1023) + wn + ni*16 + l16;
            const int hloc = nloc>>6, e = nloc&63;
            #pragma unroll
            for (int mi=0;mi<4;++mi){
                const int rowb = m0 + wm + mi*16 + quad*4;   // multiple of 4
                const int bidx = rowb >> 11, tloc = rowb & 2047;
                U4 hh, ll;
                #pragma unroll
                for (int r=0;r<4;++r) split2(acc[mi][ni][r], hh.s[r], ll.s[r]);
                const size_t adr = ((size_t)((bidx*16 + hloc)*64 + e))*T_ + tloc;
                *(uint2*)(vth + adr) = hh.v;
                *(uint2*)(vtl + adr) = ll.v;
            }
        }
    }
}

// ---- causal flash attention; q-tile 128, 8 waves, pre-split K/V ----
__global__ __launch_bounds__(512) void attn(const float* __restrict__ q,
                                            const u16* __restrict__ kh, const u16* __restrict__ kl,
                                            const u16* __restrict__ vth, const u16* __restrict__ vtl,
                                            float* __restrict__ att)
{
    __shared__ u16 Ksh[64*64], Ksl[64*64];   // [kv][e], swizzled
    __shared__ u16 Vsh[64*64], Vsl[64*64];   // [e][kv], swizzled
    __shared__ u16 Ph[8*16*64], Pl[8*16*64]; // per-wave [16][64], swizzled
    const int qi = blockIdx.x;               // q-tile of 128
    const int bh = blockIdx.y;
    const int b = bh >> 4, h = bh & 15;
    const int t = threadIdx.x;
    const int w = t>>6, lane = t&63, quad = lane>>4, l16 = lane&15;
    const int qrow = qi*128 + w*16;          // wave's absolute q base

    short8 qh_[2], ql_[2];
    {
        const float* qp = q + ((size_t)(b*T_ + qrow + l16))*D_ + h*64;
        #pragma unroll
        for (int ks=0;ks<2;++ks){
            float4 a0 = *(const float4*)(qp + ks*32 + quad*8);
            float4 a1 = *(const float4*)(qp + ks*32 + quad*8 + 4);
            S8 hh, ll;
            split2(a0.x, hh.s[0], ll.s[0]); split2(a0.y, hh.s[1], ll.s[1]);
            split2(a0.z, hh.s[2], ll.s[2]); split2(a0.w, hh.s[3], ll.s[3]);
            split2(a1.x, hh.s[4], ll.s[4]); split2(a1.y, hh.s[5], ll.s[5]);
            split2(a1.z, hh.s[6], ll.s[6]); split2(a1.w, hh.s[7], ll.s[7]);
            qh_[ks] = hh.v; ql_[ks] = ll.v;
        }
    }
    f32x4 o[4];
    #pragma unroll
    for (int i=0;i<4;++i) o[i] = (f32x4){0.f,0.f,0.f,0.f};
    float m_i[4], l_i[4];
    #pragma unroll
    for (int r=0;r<4;++r){ m_i[r] = -INFINITY; l_i[r] = 0.f; }

    u16* Pmh = Ph + w*1024;
    u16* Pml = Pl + w*1024;

    const int kvT = 2*qi + 2;
    for (int kvt=0; kvt<kvT; ++kvt){
        __syncthreads();                     // prev-iter readers done
        {
            const int row = t>>3, c = t&7;   // 512 chunks per tile-half
            const int lo = swz(row, c*8);
            const size_t gk = ((size_t)(b*T_ + kvt*64 + row))*D_ + h*64 + c*8;
            *(uint4*)(Ksh + lo) = *(const uint4*)(kh + gk);
            *(uint4*)(Ksl + lo) = *(const uint4*)(kl + gk);
            const size_t gv = ((size_t)(bh*64 + row))*T_ + kvt*64 + c*8;
            *(uint4*)(Vsh + lo) = *(const uint4*)(vth + gv);
            *(uint4*)(Vsl + lo) = *(const uint4*)(vtl + gv);
        }
        __syncthreads();

        float s[4][4];
        #pragma unroll
        for (int ni=0;ni<4;++ni){
            f32x4 sa = (f32x4){0.f,0.f,0.f,0.f};
            const int row = ni*16 + l16;
            #pragma unroll
            for (int ks=0;ks<2;++ks){
                const int co = swz(row, ks*32 + quad*8);
                short8 k8h = *(const short8*)(Ksh + co);
                short8 k8l = *(const short8*)(Ksl + co);
                sa = __builtin_amdgcn_mfma_f32_16x16x32_bf16(qh_[ks], k8h, sa, 0,0,0);
                sa = __builtin_amdgcn_mfma_f32_16x16x32_bf16(qh_[ks], k8l, sa, 0,0,0);
                sa = __builtin_amdgcn_mfma_f32_16x16x32_bf16(ql_[ks], k8h, sa, 0,0,0);
            }
            #pragma unroll
            for (int r=0;r<4;++r) s[ni][r] = sa[r]*0.125f;
        }
        // Causal mask needed iff tile max col can exceed wave MIN row.
        // (Round-4 bug: compared against qrow+15, which skipped the diagonal
        //  tile for waves whose last row == tile last col, i.e. w=3 and w=7.)
        if (kvt*64 + 63 > qrow){
            #pragma unroll
            for (int ni=0;ni<4;++ni){
                const int colabs = kvt*64 + ni*16 + l16;
                #pragma unroll
                for (int r=0;r<4;++r){
                    const int rowabs = qrow + quad*4 + r;
                    if (colabs > rowabs) s[ni][r] = -INFINITY;
                }
            }
        }
        float mnew[4], alpha[4];
        #pragma unroll
        for (int r=0;r<4;++r){
            float rm = fmaxf(fmaxf(s[0][r],s[1][r]), fmaxf(s[2][r],s[3][r]));
            #pragma unroll
            for (int off=1; off<16; off<<=1) rm = fmaxf(rm, __shfl_xor(rm, off));
            mnew[r] = fmaxf(m_i[r], rm);
            alpha[r] = __expf(m_i[r] - mnew[r]);
        }
        float p[4][4];
        #pragma unroll
        for (int ni=0;ni<4;++ni)
            #pragma unroll
            for (int r=0;r<4;++r) p[ni][r] = __expf(s[ni][r] - mnew[r]);
        #pragma unroll
        for (int r=0;r<4;++r){
            float rs = p[0][r]+p[1][r]+p[2][r]+p[3][r];
            #pragma unroll
            for (int off=1; off<16; off<<=1) rs += __shfl_xor(rs, off);
            l_i[r] = l_i[r]*alpha[r] + rs;
            m_i[r] = mnew[r];
        }
        #pragma unroll
        for (int ni=0;ni<4;++ni)
            #pragma unroll
            for (int r=0;r<4;++r) o[ni][r] *= alpha[r];
        // P: C-layout -> swizzled LDS -> A-layout
        #pragma unroll
        for (int ni=0;ni<4;++ni)
            #pragma unroll
            for (int r=0;r<4;++r){
                u16 hh, ll; split2(p[ni][r], hh, ll);
                const int po = swz(quad*4+r, ni*16 + l16);
                Pmh[po] = hh; Pml[po] = ll;
            }
        __syncthreads();                     // fence scalar writes vs vector reads
        short8 pah[2], pal[2];
        #pragma unroll
        for (int ks=0;ks<2;++ks){
            const int po = swz(l16, ks*32 + quad*8);
            pah[ks] = *(const short8*)(Pmh + po);
            pal[ks] = *(const short8*)(Pml + po);
        }
        #pragma unroll
        for (int ni=0;ni<4;++ni){
            const int row = ni*16 + l16;
            #pragma unroll
            for (int ks=0;ks<2;++ks){
                const int co = swz(row, ks*32 + quad*8);
                short8 v8h = *(const short8*)(Vsh + co);
                short8 v8l = *(const short8*)(Vsl + co);
                o[ni] = __builtin_amdgcn_mfma_f32_16x16x32_bf16(pah[ks], v8h, o[ni], 0,0,0);
                o[ni] = __builtin_amdgcn_mfma_f32_16x16x32_bf16(pah[ks], v8l, o[ni], 0,0,0);
                o[ni] = __builtin_amdgcn_mfma_f32_16x16x32_bf16(pal[ks], v8h, o[ni], 0,0,0);
            }
        }
    }
    const size_t ob = (size_t)(b*T_ + qrow);
    #pragma unroll
    for (int ni=0;ni<4;++ni){
        const int col = h*64 + ni*16 + l16;
        #pragma unroll
        for (int r=0;r<4;++r)
            att[(ob + quad*4 + r)*D_ + col] = o[ni][r] / l_i[r];
    }
}

// ---- round-3 proven f32-in GEMM (A f32, Bt f32 [N,K], bias) for out-proj ----
__global__ __launch_bounds__(256) void gemm_bt(const float* __restrict__ A,
                                               const float* __restrict__ Bt,
                                               float* __restrict__ C,
                                               const float* __restrict__ bias,
                                               int M, int N, int K)
{
    __shared__ u16 Ash[128*32], Asl[128*32];
    __shared__ u16 Bsh[128*32], Bsl[128*32];
    const int n0 = blockIdx.x*128, m0 = blockIdx.y*128;
    const int t = threadIdx.x;
    const int w = t>>6, lane = t&63, quad = lane>>4, l16 = lane&15;
    const int wm = (w>>1)*64, wn = (w&1)*64;
    f32x4 acc[4][4];
    #pragma unroll
    for (int i=0;i<4;++i)
        #pragma unroll
        for (int j=0;j<4;++j) acc[i][j] = (f32x4){0.f,0.f,0.f,0.f};
    const int kT = K >> 5;
    for (int kt=0; kt<kT; ++kt){
        const int k0 = kt*32;
        #pragma unroll
        for (int i=0;i<4;++i){
            int ci = t + 256*i;
            int row = ci>>3, c4 = ci&7;
            float4 av = *(const float4*)(A  + (size_t)(m0+row)*K + k0 + c4*4);
            float4 bv = *(const float4*)(Bt + (size_t)(n0+row)*K + k0 + c4*4);
            U4 ah, al, bh, bl;
            split2(av.x, ah.s[0], al.s[0]); split2(av.y, ah.s[1], al.s[1]);
            split2(av.z, ah.s[2], al.s[2]); split2(av.w, ah.s[3], al.s[3]);
            split2(bv.x, bh.s[0], bl.s[0]); split2(bv.y, bh.s[1], bl.s[1]);
            split2(bv.z, bh.s[2], bl.s[2]); split2(bv.w, bh.s[3], bl.s[3]);
            *(uint2*)(Ash + row*32 + c4*4) = ah.v;
            *(uint2*)(Asl + row*32 + c4*4) = al.v;
            *(uint2*)(Bsh + row*32 + c4*4) = bh.v;
            *(uint2*)(Bsl + row*32 + c4*4) = bl.v;
        }
        __syncthreads();
        short8 afh[4], afl[4], bfh[4], bfl[4];
        #pragma unroll
        for (int mi=0;mi<4;++mi){
            afh[mi] = *(const short8*)(Ash + (wm+mi*16+l16)*32 + quad*8);
            afl[mi] = *(const short8*)(Asl + (wm+mi*16+l16)*32 + quad*8);
        }
        #pragma unroll
        for (int ni=0;ni<4;++ni){
            bfh[ni] = *(const short8*)(Bsh + (wn+ni*16+l16)*32 + quad*8);
            bfl[ni] = *(const short8*)(Bsl + (wn+ni*16+l16)*32 + quad*8);
        }
        #pragma unroll
        for (int mi=0;mi<4;++mi)
            #pragma unroll
            for (int ni=0;ni<4;++ni){
                acc[mi][ni] = __builtin_amdgcn_mfma_f32_16x16x32_bf16(afh[mi], bfh[ni], acc[mi][ni], 0,0,0);
                acc[mi][ni] = __builtin_amdgcn_mfma_f32_16x16x32_bf16(afh[mi], bfl[ni], acc[mi][ni], 0,0,0);
                acc[mi][ni] = __builtin_amdgcn_mfma_f32_16x16x32_bf16(afl[mi], bfh[ni], acc[mi][ni], 0,0,0);
            }
        __syncthreads();
    }
    #pragma unroll
    for (int ni=0;ni<4;++ni){
        const int col = n0 + wn + ni*16 + l16;
        const float bv = bias ? bias[col] : 0.f;
        #pragma unroll
        for (int mi=0;mi<4;++mi){
            const int row = m0 + wm + mi*16 + quad*4;
            #pragma unroll
            for (int r=0;r<4;++r)
                C[(size_t)(row+r)*N + col] = acc[mi][ni][r] + bv;
        }
    }
}

extern "C" void kernel_launch(void* const* d_in, const int* in_sizes, int n_in,
                              void* d_out, int out_size, void* d_ws, size_t ws_size,
                              hipStream_t stream)
{
    const float* x  = (const float*)d_in[0];
    const float* Wq = (const float*)d_in[1];
    const float* Wk = (const float*)d_in[2];
    const float* Wv = (const float*)d_in[3];
    const float* Wp = (const float*)d_in[4];
    const float* bp = (const float*)d_in[5];
    float* out = (float*)d_out;

    // workspace layout (134.2 MB total, matches round-3 proven footprint)
    float* q   = (float*)d_ws;                 // [BT][1024] f32
    u16*  kh   = (u16*)(q + (size_t)BT*D_);    // [BT][1024] u16
    u16*  kl   = kh + (size_t)BT*D_;
    u16*  vth  = kl + (size_t)BT*D_;           // [64bh][64e][2048t] u16
    u16*  vtl  = vth + (size_t)BT*D_;
    float* att = (float*)(vtl + (size_t)BT*D_);// [BT][1024] f32
    // Wt (split) aliases the att region: dead before attn writes att
    u16*  Wth  = (u16*)att;                    // [3072][1024] u16 (6.3 MB)
    u16*  Wtl  = Wth + (size_t)3072*D_;

    pack_w  <<<dim3(16,16,3), 256, 0, stream>>>(Wq, Wk, Wv, Wth, Wtl);
    gemm_qkv<<<dim3(24, BT/128), 256, 0, stream>>>(x, Wth, Wtl, q, kh, kl, vth, vtl);
    attn    <<<dim3(T_/128, B_*H_), 512, 0, stream>>>(q, kh, kl, vth, vtl, att);
    gemm_bt <<<dim3(8, BT/128), 256, 0, stream>>>(att, Wp, out, bp, BT, D_, D_);
}